// Round 2
// baseline (1850.383 us; speedup 1.0000x reference)
//
#include <hip/hip_runtime.h>

// AttentionalGraphAggregation on MI355X — round 2.
// Pipeline: memset(out,denom) -> K1 gate+exp+denom (bf16 MFMA, fused segmented
// softmax denominator) -> alpha (tiny) -> K2 transform GEMM + alpha-weighted
// run-batched segmented scatter.
// No max-stabilization: gate sigma ~0.23, max|gate| ~1.3 over 1M rows, exp is
// safe in fp32 and alpha = e/sum(e) is shift-invariant.
// x read twice (2.05 GB) => HBM floor ~330 us.

using bf16x8 = __attribute__((ext_vector_type(8))) short;   // 8 bf16 (4 VGPRs)
using short8 = __attribute__((ext_vector_type(8))) short;
using f32x16 = __attribute__((ext_vector_type(16))) float;  // 32x32 MFMA acc

// float -> bf16 bits, round-to-nearest-even (inputs finite)
__device__ inline short f2b(float f) {
  unsigned u = __builtin_bit_cast(unsigned, f);
  unsigned r = (u + 0x7FFFu + ((u >> 16) & 1u)) >> 16;
  return (short)(unsigned short)r;
}

// ---------------------------------------------------------------------------
// K1: e[i] = exp(relu(x@W1+b1)@W2 + b2); denom[seg] += segmented run sums.
// 256 thr = 4 waves; wave w owns HID strip [32w,32w+32); batch = 32 rows.
// Double-buffered LDS, register prefetch, ONE barrier per batch.
// MFMA 32x32x16 bf16: A[m][k] m=lane&31,k=(lane>>5)*8+j; B[k][n] n=lane&31;
// C row=(reg&3)+8*(reg>>2)+4*(lane>>5), col=lane&31.  (verified R1: passed)
// ---------------------------------------------------------------------------
__global__ __launch_bounds__(256, 3) void gate_e_denom_kernel(
    const float* __restrict__ x, const int* __restrict__ idx,
    const float* __restrict__ W1, const float* __restrict__ b1,
    const float* __restrict__ W2, const float* __restrict__ b2p,
    float* __restrict__ e, float* __restrict__ denom, int nbatch)
{
  __shared__ unsigned short xt[2][32][264];  // bf16 bits, padded stride
  __shared__ float gpart[2][4][32];
  const int tid = threadIdx.x;
  const int wave = tid >> 6, lane = tid & 63;
  const int half = lane >> 5, l32 = lane & 31;
  const int col = wave * 32 + l32;  // 0..127 of HID

  bf16x8 bf[16];
#pragma unroll
  for (int t = 0; t < 16; ++t)
#pragma unroll
    for (int j = 0; j < 8; ++j)
      bf[t][j] = f2b(W1[(t * 16 + half * 8 + j) * 128 + col]);
  const float b1v = b1[col];
  const float w2v = W2[col];
  const float b2v = b2p[0];

  const int stride = gridDim.x;
  const int tr = tid >> 3, c0 = (tid & 7) * 32;  // staging: row, col-group

  int b = blockIdx.x;
  float4 pf[8];
  int seg_cur = 0, seg_prev = 0, prev_b = -1;
  if (b < nbatch) {
    const float4* xp = (const float4*)(x + (size_t)(b * 32 + tr) * 256 + c0);
#pragma unroll
    for (int q = 0; q < 8; ++q) pf[q] = xp[q];
    if (tid < 32) seg_cur = idx[b * 32 + tid];
  }

  int p = 0;
  for (; b < nbatch; b += stride, p ^= 1) {
    // stage current batch regs -> LDS buf p
    {
      short8* dst = (short8*)&xt[p][tr][c0];
#pragma unroll
      for (int q = 0; q < 4; ++q) {
        float4 f0 = pf[2 * q], f1 = pf[2 * q + 1];
        short8 w;
        w[0] = f2b(f0.x); w[1] = f2b(f0.y); w[2] = f2b(f0.z); w[3] = f2b(f0.w);
        w[4] = f2b(f1.x); w[5] = f2b(f1.y); w[6] = f2b(f1.z); w[7] = f2b(f1.w);
        dst[q] = w;
      }
    }
    __syncthreads();
    // finalize PREVIOUS batch: gate row sums -> exp -> e[] + denom atomics
    if (prev_b >= 0 && tid < 32) {
      const float g = gpart[p ^ 1][0][tid] + gpart[p ^ 1][1][tid] +
                      gpart[p ^ 1][2][tid] + gpart[p ^ 1][3][tid] + b2v;
      float ev = __expf(g);
      e[prev_b * 32 + tid] = ev;
      const int s = seg_prev;
      float sv = ev;
#pragma unroll
      for (int d = 1; d < 32; d <<= 1) {
        float o = __shfl_up(sv, d, 64);
        int os = __shfl_up(s, d, 64);
        if (tid >= d && os == s) sv += o;
      }
      const int ns = __shfl_down(s, 1, 64);
      if (tid == 31 || ns != s) atomicAdd(&denom[s], sv);
    }
    seg_prev = seg_cur;
    prev_b = b;
    // prefetch next batch (loads overlap MFMA below)
    const int nb = b + stride;
    if (nb < nbatch) {
      const float4* xp = (const float4*)(x + (size_t)(nb * 32 + tr) * 256 + c0);
#pragma unroll
      for (int q = 0; q < 8; ++q) pf[q] = xp[q];
      if (tid < 32) seg_cur = idx[nb * 32 + tid];
    }
    // compute: h = relu(x@W1+b1); partial gate = h*W2 reduced over 32 cols
    f32x16 acc = (f32x16)0.0f;
#pragma unroll
    for (int t = 0; t < 16; ++t) {
      bf16x8 a = *(const bf16x8*)&xt[p][l32][t * 16 + half * 8];
      acc = __builtin_amdgcn_mfma_f32_32x32x16_bf16(a, bf[t], acc, 0, 0, 0);
    }
#pragma unroll
    for (int reg = 0; reg < 16; ++reg) {
      const int r = (reg & 3) + 8 * (reg >> 2) + 4 * half;
      float h = acc[reg] + b1v;
      h = h > 0.f ? h : 0.f;
      float pv = h * w2v;
#pragma unroll
      for (int d = 1; d < 32; d <<= 1) pv += __shfl_xor(pv, d, 64);
      if (l32 == 0) gpart[p][wave][r] = pv;
    }
  }
  // tail: finalize last batch
  __syncthreads();
  if (prev_b >= 0 && tid < 32) {
    const float g = gpart[p ^ 1][0][tid] + gpart[p ^ 1][1][tid] +
                    gpart[p ^ 1][2][tid] + gpart[p ^ 1][3][tid] + b2v;
    float ev = __expf(g);
    e[prev_b * 32 + tid] = ev;
    const int s = seg_prev;
    float sv = ev;
#pragma unroll
    for (int d = 1; d < 32; d <<= 1) {
      float o = __shfl_up(sv, d, 64);
      int os = __shfl_up(s, d, 64);
      if (tid >= d && os == s) sv += o;
    }
    const int ns = __shfl_down(s, 1, 64);
    if (tid == 31 || ns != s) atomicAdd(&denom[s], sv);
  }
}

// ---------------------------------------------------------------------------
// K1.5: alpha[i] = e[i] / max(denom[idx[i]], 1e-16)
// ---------------------------------------------------------------------------
__global__ __launch_bounds__(256) void alpha_kernel(
    const float* __restrict__ e, const int* __restrict__ idx,
    const float* __restrict__ denom, float* __restrict__ alpha, int N)
{
  const int i = blockIdx.x * 256 + threadIdx.x;
  if (i < N) alpha[i] = e[i] / fmaxf(denom[idx[i]], 1e-16f);
}

// ---------------------------------------------------------------------------
// K2: t = relu(x@Wt+bt); out[seg] += alpha*t.  512 thr = 8 waves, wave w owns
// OUT strip [32w,32w+32); batch = 32 rows; double-buffered, 1 barrier/batch.
// Sorted index => ~1.5 runs/batch => ~1 coalesced 32-lane atomicAdd per run.
// ---------------------------------------------------------------------------
__global__ __launch_bounds__(512) void transform_kernel(
    const float* __restrict__ x, const int* __restrict__ idx,
    const float* __restrict__ Wt, const float* __restrict__ bt,
    const float* __restrict__ alpha, float* __restrict__ out, int nbatch)
{
  __shared__ unsigned short xt[2][32][264];
  __shared__ float al_s[2][32];
  __shared__ int seg_s[2][32];
  const int tid = threadIdx.x;
  const int wave = tid >> 6, lane = tid & 63;
  const int half = lane >> 5, l32 = lane & 31;
  const int col = wave * 32 + l32;  // 0..255

  bf16x8 bf[16];
#pragma unroll
  for (int t = 0; t < 16; ++t)
#pragma unroll
    for (int j = 0; j < 8; ++j)
      bf[t][j] = f2b(Wt[(t * 16 + half * 8 + j) * 256 + col]);
  const float btv = bt[col];

  const int stride = gridDim.x;
  const int tr = tid >> 4, c0 = (tid & 15) * 16;  // staging: row, col-group

  int b = blockIdx.x;
  float4 pf[4];
  int sg_cur = 0;
  float al_cur = 0.f;
  if (b < nbatch) {
    const float4* xp = (const float4*)(x + (size_t)(b * 32 + tr) * 256 + c0);
#pragma unroll
    for (int q = 0; q < 4; ++q) pf[q] = xp[q];
    if (tid < 32) {
      sg_cur = idx[b * 32 + tid];
      al_cur = alpha[b * 32 + tid];
    }
  }

  int p = 0;
  for (; b < nbatch; b += stride, p ^= 1) {
    {
      short8* dst = (short8*)&xt[p][tr][c0];
#pragma unroll
      for (int q = 0; q < 2; ++q) {
        float4 f0 = pf[2 * q], f1 = pf[2 * q + 1];
        short8 w;
        w[0] = f2b(f0.x); w[1] = f2b(f0.y); w[2] = f2b(f0.z); w[3] = f2b(f0.w);
        w[4] = f2b(f1.x); w[5] = f2b(f1.y); w[6] = f2b(f1.z); w[7] = f2b(f1.w);
        dst[q] = w;
      }
      if (tid < 32) {
        seg_s[p][tid] = sg_cur;
        al_s[p][tid] = al_cur;
      }
    }
    __syncthreads();
    // prefetch next batch (overlaps MFMA)
    const int nb = b + stride;
    if (nb < nbatch) {
      const float4* xp = (const float4*)(x + (size_t)(nb * 32 + tr) * 256 + c0);
#pragma unroll
      for (int q = 0; q < 4; ++q) pf[q] = xp[q];
      if (tid < 32) {
        sg_cur = idx[nb * 32 + tid];
        al_cur = alpha[nb * 32 + tid];
      }
    }
    f32x16 acc = (f32x16)0.0f;
#pragma unroll
    for (int t = 0; t < 16; ++t) {
      bf16x8 a = *(const bf16x8*)&xt[p][l32][t * 16 + half * 8];
      acc = __builtin_amdgcn_mfma_f32_32x32x16_bf16(a, bf[t], acc, 0, 0, 0);
    }
#pragma unroll
    for (int reg = 0; reg < 16; ++reg) {
      const int r = (reg & 3) + 8 * (reg >> 2) + 4 * half;
      float tv = acc[reg] + btv;
      tv = tv > 0.f ? tv : 0.f;
      acc[reg] = tv * al_s[p][r];
    }
    // per-run reduce over rows, one 32-lane atomicAdd per (run, col)
    int pos = 0;
    while (pos < 32) {
      const int s = seg_s[p][pos];
      int end = pos + 1;
      while (end < 32 && seg_s[p][end] == s) ++end;
      float part = 0.f;
#pragma unroll
      for (int reg = 0; reg < 16; ++reg) {
        const int r = (reg & 3) + 8 * (reg >> 2) + 4 * half;
        part += (r >= pos && r < end) ? acc[reg] : 0.f;
      }
      part += __shfl_xor(part, 32, 64);  // combine half-wave row groups
      if (half == 0) atomicAdd(&out[(size_t)s * 256 + col], part);
      pos = end;
    }
  }
}

// ---------------------------------------------------------------------------
extern "C" void kernel_launch(void* const* d_in, const int* in_sizes, int n_in,
                              void* d_out, int out_size, void* d_ws, size_t ws_size,
                              hipStream_t stream) {
  const float* x   = (const float*)d_in[0];
  const int*   idx = (const int*)d_in[1];
  const float* W1  = (const float*)d_in[3];
  const float* b1  = (const float*)d_in[4];
  const float* W2  = (const float*)d_in[5];
  const float* b2  = (const float*)d_in[6];
  const float* Wt  = (const float*)d_in[7];
  const float* bt  = (const float*)d_in[8];
  float* out = (float*)d_out;

  const int N = in_sizes[0] / 256;
  const int S = out_size / 256;

  // ws: e[N] | alpha[N] | denom[S]
  float* e = (float*)d_ws;
  float* alpha = e + N;
  float* denom = alpha + N;

  hipMemsetAsync(d_out, 0, (size_t)out_size * sizeof(float), stream);
  hipMemsetAsync(denom, 0, (size_t)S * sizeof(float), stream);

  gate_e_denom_kernel<<<1024, 256, 0, stream>>>(x, idx, W1, b1, W2, b2, e, denom, N / 32);
  alpha_kernel<<<(N + 255) / 256, 256, 0, stream>>>(e, idx, denom, alpha, N);
  transform_kernel<<<768, 512, 0, stream>>>(x, idx, Wt, bt, alpha, out, N / 32);
}